// Round 8
// baseline (8206.084 us; speedup 1.0000x reference)
//
#include <hip/hip_runtime.h>

#define NB 512
#define NL 512
#define NK 103
#define NH 512
#define NI 105
#define XROW (NL * NK)

typedef _Float16 half8 __attribute__((ext_vector_type(8)));
typedef _Float16 half4 __attribute__((ext_vector_type(4)));
typedef float floatx4 __attribute__((ext_vector_type(4)));
typedef int int4v __attribute__((ext_vector_type(4)));

union U16 { int4v i; half8 h; unsigned long long u[2]; };

// LDS layout (bytes)
#define H_SSTR 2064           // slice stride: 512 rows... (64 rows x 32B) + 16B pad
#define XB_STR 136
#define B2_STR 136
#define YST_STR 72
#define Y2_STR 16
#define OFF_H   0             // 32 slices x 2064 = 66048: staged h tile
#define OFF_XB  66048         // 2 x 64 x 136 halves = 34816
#define OFF_B2  100864        // 17408
#define OFF_YST 118272        // 9216
#define OFF_Y2  127488        // 2048 (aliased as HTX after mid-step sync)
#define OFF_FR  129536        // 448 floats
#define SMEM_BYTES 131328     // forces 1 block/CU; needs opt-in attribute

#define SPIN_MAX (1 << 20)

#define A_LOAD(p)  __hip_atomic_load((p),  __ATOMIC_RELAXED, __HIP_MEMORY_SCOPE_AGENT)
#define A_STORE(p, v) __hip_atomic_store((p), (v), __ATOMIC_RELAXED, __HIP_MEMORY_SCOPE_AGENT)

// ws map: [0,4096) flags[8][32] spaced 4 dwords; [4096, 4096+2x512KB) hbuf
// double buffer, slice-major: slice s at +s*16384, row r at +r*32 (16 f16 cols).

__device__ __forceinline__ float fast_sigmoid(float v) {
  v = fminf(fmaxf(v, -30.f), 30.f);
  return __builtin_amdgcn_rcpf(1.f + __expf(-v));
}
__device__ __forceinline__ float fast_tanh(float v) {
  v = fminf(fmaxf(v, -15.f), 15.f);
  float e = __expf(-2.f * v);
  return (1.f - e) * __builtin_amdgcn_rcpf(1.f + e);
}

__global__ void __launch_bounds__(256, 1)
lstm_persist(const float* __restrict__ x, const float* __restrict__ pos,
             const float* __restrict__ h0, const float* __restrict__ c0,
             const float* __restrict__ Wih, const float* __restrict__ Whh,
             const float* __restrict__ bih, const float* __restrict__ bhh,
             const float* __restrict__ W1, const float* __restrict__ b1,
             const float* __restrict__ W2, const float* __restrict__ b2,
             const float* __restrict__ W3, const float* __restrict__ b3,
             float* __restrict__ out, void* __restrict__ ws)
{
  extern __shared__ char smem[];
  _Float16* B2s = (_Float16*)(smem + OFF_B2);
  _Float16* YST = (_Float16*)(smem + OFF_YST);
  _Float16* Y2  = (_Float16*)(smem + OFF_Y2);
  _Float16* HTX = Y2;   // reuse: Y2 dead before HTX writes begin
  float* FR  = (float*)(smem + OFF_FR);
  float* b1s = FR;          // 64
  float* b2s = FR + 64;     // 16
  float* w3s = FR + 80;     // 32
  float* b3s = FR + 112;    // 2
  float* wy0 = FR + 114;    // 64
  float* wy1 = FR + 178;    // 64
  float* bgs = FR + 242;    // 64
  float* ypres = FR + 306;  // 128
  volatile int* abflag = (volatile int*)(FR + 440);

  const int tid = threadIdx.x;
  const int g  = blockIdx.x >> 5;   // batch group: rows 64g..64g+63
  const int cs = blockIdx.x & 31;   // h-column slice: 16cs..16cs+15
  const int w  = tid >> 6, l = tid & 63;
  const int c16 = l & 15, q = l >> 4;
  const int rh = w >> 1;            // row half (32 rows)
  const int ch = w & 1;             // 0 = gates, 1 = MLP(W1)

  unsigned* flags = (unsigned*)ws;
  char* hbase = (char*)ws + 4096;

  if (tid == 0) *abflag = 0;
  // ---- zero xbuf (incl. zero-pad cols 103..127) ----
  {
    unsigned* xz = (unsigned*)(smem + OFF_XB);
    for (int i = tid; i < 8704; i += 256) xz[i] = 0;
  }
  // ---- W_ih x-part -> LDS fp16 ----
  for (int idx = tid; idx < 64 * 128; idx += 256) {
    int cc = idx >> 7, k = idx & 127;
    int gr = (cc >> 4) * NH + cs * 16 + (cc & 15);
    float v = (k < NK) ? Wih[(size_t)gr * NI + k] : 0.f;
    B2s[cc * B2_STR + k] = (_Float16)v;
  }
  // ---- small fp32 tables ----
  if (tid < 64) {
    int gr = (tid >> 4) * NH + cs * 16 + (tid & 15);
    wy0[tid] = Wih[(size_t)gr * NI + 103];
    wy1[tid] = Wih[(size_t)gr * NI + 104];
    bgs[tid] = bih[gr] + bhh[gr];
    b1s[tid] = b1[tid];
  }
  if (tid < 16) b2s[tid] = b2[tid];
  if (tid < 32) w3s[tid] = W3[tid];
  if (tid < 2)  b3s[tid] = b3[tid];

  // ---- h0 -> hbuf[0] slice cs (agent stores -> MALL) ----
  {
    const int r = tid >> 2, hb = tid & 3;
    const float* src = h0 + (size_t)(64 * g + r) * NH + cs * 16 + hb * 4;
    union { unsigned long long u; half4 h; } cv;
    cv.h[0] = (_Float16)src[0]; cv.h[1] = (_Float16)src[1];
    cv.h[2] = (_Float16)src[2]; cv.h[3] = (_Float16)src[3];
    A_STORE((unsigned long long*)(hbase + (size_t)cs * 16384
                                  + (size_t)(64 * g + r) * 32 + hb * 8), cv.u);
  }

  // ---- B weight fragments -> registers (held all 512 steps) ----
  half8 bfr[4][16];
  #pragma unroll
  for (int ct = 0; ct < 4; ++ct) {
    const int rown = ch ? (ct * 16 + c16) : (ct * NH + cs * 16 + c16);
    const float* rp = (ch ? W1 : Whh) + (size_t)rown * NH;
    #pragma unroll
    for (int kk = 0; kk < 16; ++kk) {
      const float* p = rp + kk * 32 + q * 8;
      floatx4 f0 = *(const floatx4*)(p);
      floatx4 f1 = *(const floatx4*)(p + 4);
      half8 hv;
      hv[0]=(_Float16)f0[0]; hv[1]=(_Float16)f0[1]; hv[2]=(_Float16)f0[2]; hv[3]=(_Float16)f0[3];
      hv[4]=(_Float16)f1[0]; hv[5]=(_Float16)f1[1]; hv[6]=(_Float16)f1[2]; hv[7]=(_Float16)f1[3];
      bfr[ct][kk] = hv;
    }
  }
  half8 w2f[2];
  if (ch) {
    #pragma unroll
    for (int kk = 0; kk < 2; ++kk) {
      const float* p = W2 + c16 * 64 + kk * 32 + q * 8;
      floatx4 f0 = *(const floatx4*)(p);
      floatx4 f1 = *(const floatx4*)(p + 4);
      half8 hv;
      hv[0]=(_Float16)f0[0]; hv[1]=(_Float16)f0[1]; hv[2]=(_Float16)f0[2]; hv[3]=(_Float16)f0[3];
      hv[4]=(_Float16)f1[0]; hv[5]=(_Float16)f1[1]; hv[6]=(_Float16)f1[2]; hv[7]=(_Float16)f1[3];
      w2f[kk] = hv;
    }
  }
  float cacc[2][4];
  if (!ch) {
    #pragma unroll
    for (int rt = 0; rt < 2; ++rt)
      #pragma unroll
      for (int reg = 0; reg < 4; ++reg)
        cacc[rt][reg] = c0[(size_t)(64 * g + 32 * rh + 16 * rt + q * 4 + reg) * NH + cs * 16 + c16];
  }

  // coalesced x_t -> LDS f16 stager (gate waves; 2 lanes per row)
  auto xstage = [&](int t1) {
    _Float16* xb = (_Float16*)(smem + OFF_XB) + (size_t)(t1 & 1) * 64 * XB_STR;
    const int row = 32 * rh + (l >> 1);
    const int p = l & 1;
    const float* src = x + (size_t)(64 * g + row) * XROW + (size_t)t1 * NK + p * 52;
    _Float16* dst = xb + row * XB_STR + p * 52;
    const int nfull = p ? 12 : 13;
    for (int cnk = 0; cnk < nfull; ++cnk) {
      float f0 = src[cnk * 4 + 0], f1 = src[cnk * 4 + 1];
      float f2 = src[cnk * 4 + 2], f3 = src[cnk * 4 + 3];
      half4 hv; hv[0]=(_Float16)f0; hv[1]=(_Float16)f1; hv[2]=(_Float16)f2; hv[3]=(_Float16)f3;
      *(half4*)(dst + cnk * 4) = hv;
    }
    if (p) {
      dst[48] = (_Float16)src[48];
      dst[49] = (_Float16)src[49];
      dst[50] = (_Float16)src[50];
    }
  };

  // flag publish: caller guarantees a prior __syncthreads drained publishes
  auto fpub = [&](unsigned val) {
    if (tid == 0) A_STORE(flags + ((g << 5) + cs) * 4, val);
  };

  // dataflow staging: poll producer-s flag >= need, then pull slice s (this
  // thread's 8-row chunk) from MALL into the LDS H tile. 8 threads per slice.
  auto hstage = [&](int par, unsigned need) {
    const int s = tid & 31, rb = tid >> 5;
    {
      unsigned* f = flags + ((g << 5) + s) * 4;
      int spins = 0;
      while (A_LOAD(f) < need) {
        __builtin_amdgcn_s_sleep(1);
        if (++spins > SPIN_MAX) { *abflag = 1; break; }
      }
    }
    const char* gsrc = hbase + (size_t)par * 524288
                     + (size_t)s * 16384 + (size_t)(64 * g + rb * 8) * 32;
    char* ldst = smem + OFF_H + s * H_SSTR + rb * 256;
    unsigned long long v[32];
    #pragma unroll
    for (int j = 0; j < 8; ++j) {
      const unsigned long long* up = (const unsigned long long*)(gsrc + j * 32);
      v[j*4+0] = A_LOAD(up);     v[j*4+1] = A_LOAD(up + 1);
      v[j*4+2] = A_LOAD(up + 2); v[j*4+3] = A_LOAD(up + 3);
    }
    #pragma unroll
    for (int j = 0; j < 8; ++j) {
      U16 a, b;
      a.u[0] = v[j*4+0]; a.u[1] = v[j*4+1];
      b.u[0] = v[j*4+2]; b.u[1] = v[j*4+3];
      *(int4v*)(ldst + j * 32)      = a.i;
      *(int4v*)(ldst + j * 32 + 16) = b.i;
    }
  };

  __syncthreads();          // xbuf zero + h0 stores drained (per-wave vmcnt)
  if (!ch) xstage(0);       // x_0 -> xbuf[0]
  __syncthreads();
  fpub(1);                  // h0 slice published
  hstage(0, 1);             // pull full h0 tile -> LDS
  __syncthreads();
  if (*abflag) return;

  // iter t: all waves MFMA over staged h_{t-1}; MLP waves finish y_{t-1};
  // gate waves add x_t + feedback, update c -> h_t; publish; dataflow-stage.
  for (int t = 0; t <= NL; ++t) {

    // ---- phase 1: K=512 over h_{t-1} from LDS tile; B from registers ----
    floatx4 acc[4][2] = {};
    {
      const char* base0 = smem + OFF_H + (q >> 1) * H_SSTR
                        + (32 * rh + c16) * 32 + (q & 1) * 16;
      #pragma unroll
      for (int kk = 0; kk < 16; ++kk) {
        const char* bp = base0 + kk * 2 * H_SSTR;
        half8 a0 = *(const half8*)(bp);
        half8 a1 = *(const half8*)(bp + 16 * 32);
        #pragma unroll
        for (int ct = 0; ct < 4; ++ct) {
          acc[ct][0] = __builtin_amdgcn_mfma_f32_16x16x32_f16(a0, bfr[ct][kk], acc[ct][0], 0, 0, 0);
          acc[ct][1] = __builtin_amdgcn_mfma_f32_16x16x32_f16(a1, bfr[ct][kk], acc[ct][1], 0, 0, 0);
        }
      }
    }

    // ---- phase 2 (gate waves): x_t contribution, K=128 from LDS ----
    if (!ch && t < NL) {
      const _Float16* xb = (const _Float16*)(smem + OFF_XB) + (size_t)(t & 1) * 64 * XB_STR;
      #pragma unroll
      for (int kb = 0; kb < 4; ++kb) {
        half8 ax[2];
        #pragma unroll
        for (int rt = 0; rt < 2; ++rt)
          ax[rt] = *(const half8*)(xb + (32 * rh + 16 * rt + c16) * XB_STR + kb * 32 + q * 8);
        #pragma unroll
        for (int ct = 0; ct < 4; ++ct) {
          half8 bf = *(const half8*)(B2s + (ct * 16 + c16) * B2_STR + kb * 32 + q * 8);
          #pragma unroll
          for (int rt = 0; rt < 2; ++rt)
            acc[ct][rt] = __builtin_amdgcn_mfma_f32_16x16x32_f16(ax[rt], bf, acc[ct][rt], 0, 0, 0);
        }
      }
      if (t + 1 < NL) xstage(t + 1);
    }

    // ---- MLP waves: y_{t-1} (or pos init at t==0) ----
    if (ch) {
      if (t == 0) {
        if (l < 32) {
          int row = 32 * rh + l;
          const float* pp = pos + (size_t)(64 * g + row) * (NL * 2);
          ypres[row * 2 + 0] = pp[0];
          ypres[row * 2 + 1] = pp[1];
        }
      } else {
        #pragma unroll
        for (int ct = 0; ct < 4; ++ct)
          #pragma unroll
          for (int rt = 0; rt < 2; ++rt)
            #pragma unroll
            for (int reg = 0; reg < 4; ++reg) {
              int row = 32 * rh + 16 * rt + q * 4 + reg;
              float v = acc[ct][rt][reg] + b1s[ct * 16 + c16];
              YST[row * YST_STR + ct * 16 + c16] = (_Float16)fmaxf(v, 0.f);
            }
        floatx4 a2c[2] = {};
        #pragma unroll
        for (int kk2 = 0; kk2 < 2; ++kk2)
          #pragma unroll
          for (int rt = 0; rt < 2; ++rt) {
            half8 af = *(const half8*)(YST + (32 * rh + 16 * rt + c16) * YST_STR + kk2 * 32 + q * 8);
            a2c[rt] = __builtin_amdgcn_mfma_f32_16x16x32_f16(af, w2f[kk2], a2c[rt], 0, 0, 0);
          }
        #pragma unroll
        for (int rt = 0; rt < 2; ++rt)
          #pragma unroll
          for (int reg = 0; reg < 4; ++reg) {
            int row = 32 * rh + 16 * rt + q * 4 + reg;
            float v = a2c[rt][reg] + b2s[c16];
            Y2[row * Y2_STR + c16] = (_Float16)fmaxf(v, 0.f);
          }
        if (l < 32) {
          int row = 32 * rh + l;
          float y0 = b3s[0], y1 = b3s[1];
          #pragma unroll
          for (int k = 0; k < 16; ++k) {
            float vv = (float)Y2[row * Y2_STR + k];
            y0 += vv * w3s[k];
            y1 += vv * w3s[16 + k];
          }
          y0 = fmaxf(y0, 0.f); y1 = fmaxf(y1, 0.f);
          ypres[row * 2 + 0] = y0;
          ypres[row * 2 + 1] = y1;
          if (cs == 0) {
            float2* op = (float2*)(out + (size_t)(64 * g + row) * (NL * 2) + (size_t)(t - 1) * 2);
            *op = make_float2(y0, y1);
          }
        }
      }
    }
    __syncthreads();  // ypres ready; Y2 reads done (HTX may overwrite)

    // ---- gate epilogue: feedback + bias + LSTM cell; h_t -> LDS tile ----
    if (!ch && t < NL) {
      #pragma unroll
      for (int rt = 0; rt < 2; ++rt)
        #pragma unroll
        for (int reg = 0; reg < 4; ++reg) {
          int rl = 32 * rh + 16 * rt + q * 4 + reg;
          float yp0 = ypres[rl * 2], yp1 = ypres[rl * 2 + 1];
          float gi = acc[0][rt][reg] + bgs[c16]      + yp0 * wy0[c16]      + yp1 * wy1[c16];
          float gf = acc[1][rt][reg] + bgs[16 + c16] + yp0 * wy0[16 + c16] + yp1 * wy1[16 + c16];
          float gg = acc[2][rt][reg] + bgs[32 + c16] + yp0 * wy0[32 + c16] + yp1 * wy1[32 + c16];
          float go = acc[3][rt][reg] + bgs[48 + c16] + yp0 * wy0[48 + c16] + yp1 * wy1[48 + c16];
          float iv = fast_sigmoid(gi);
          float fv = fast_sigmoid(gf);
          float gv = fast_tanh(gg);
          float ov = fast_sigmoid(go);
          float cn = fv * cacc[rt][reg] + iv * gv;
          cacc[rt][reg] = cn;
          float hn = ov * fast_tanh(cn);
          HTX[rl * 16 + c16] = (_Float16)hn;
          if (t == NL - 1) {
            out[(size_t)(NB * NL * 2) + (size_t)(64 * g + rl) * NH + cs * 16 + c16] = hn;
            out[(size_t)(NB * NL * 2) + (size_t)(NB * NH) + (size_t)(64 * g + rl) * NH + cs * 16 + c16] = cn;
          }
        }
    }

    if (t < NL) {
      __syncthreads();  // HTX complete (and all H-tile reads of this iter done)
      // publish h_t slice: 256 threads x 8B agent stores, slice-major
      {
        const int r = tid >> 2, hb = tid & 3;
        char* dst = hbase + (size_t)((t + 1) & 1) * 524288
                  + (size_t)cs * 16384 + (size_t)(64 * g + r) * 32 + hb * 8;
        unsigned long long v = *(const unsigned long long*)(HTX + r * 16 + hb * 4);
        A_STORE((unsigned long long*)dst, v);
      }
      __syncthreads();          // drain publishes (vmcnt 0 in every wave)
      fpub((unsigned)(t + 2));  // raise our flag
      hstage((t + 1) & 1, (unsigned)(t + 2));  // dataflow pull of next tile
      __syncthreads();          // LDS tile ready
      if (*abflag) return;
    }
  }
}

extern "C" void kernel_launch(void* const* d_in, const int* in_sizes, int n_in,
                              void* d_out, int out_size, void* d_ws, size_t ws_size,
                              hipStream_t stream) {
  (void)in_sizes; (void)n_in; (void)out_size; (void)ws_size;
  const float* x   = (const float*)d_in[0];
  const float* pos = (const float*)d_in[1];
  const float* h0  = (const float*)d_in[2];
  const float* c0  = (const float*)d_in[3];
  const float* Wih = (const float*)d_in[4];
  const float* Whh = (const float*)d_in[5];
  const float* bih = (const float*)d_in[6];
  const float* bhh = (const float*)d_in[7];
  const float* W1  = (const float*)d_in[8];
  const float* b1  = (const float*)d_in[9];
  const float* W2  = (const float*)d_in[10];
  const float* b2  = (const float*)d_in[11];
  const float* W3  = (const float*)d_in[12];
  const float* b3  = (const float*)d_in[13];
  float* out = (float*)d_out;

  hipMemsetAsync(d_ws, 0, 4096, stream);  // flags

  hipFuncSetAttribute(reinterpret_cast<const void*>(lstm_persist),
                      hipFuncAttributeMaxDynamicSharedMemorySize, SMEM_BYTES);

  void* args[] = { (void*)&x, (void*)&pos, (void*)&h0, (void*)&c0,
                   (void*)&Wih, (void*)&Whh, (void*)&bih, (void*)&bhh,
                   (void*)&W1, (void*)&b1, (void*)&W2, (void*)&b2,
                   (void*)&W3, (void*)&b3, (void*)&out, (void*)&d_ws };

  hipError_t err = hipLaunchCooperativeKernel(
      reinterpret_cast<void*>(lstm_persist),
      dim3(256, 1, 1), dim3(256, 1, 1), args, (unsigned)SMEM_BYTES, stream);
  if (err != hipSuccess) {
    (void)hipGetLastError();
    lstm_persist<<<dim3(256, 1, 1), dim3(256, 1, 1), SMEM_BYTES, stream>>>(
        x, pos, h0, c0, Wih, Whh, bih, bhh, W1, b1, W2, b2, W3, b3, out, d_ws);
  }
}

// Round 9
// 5453.331 us; speedup vs baseline: 1.5048x; 1.5048x over previous
//
#include <hip/hip_runtime.h>

#define NB 512
#define NL 512
#define NK 103
#define NH 512
#define NI 105
#define XROW (NL * NK)

typedef _Float16 half8 __attribute__((ext_vector_type(8)));
typedef _Float16 half4 __attribute__((ext_vector_type(4)));
typedef float floatx4 __attribute__((ext_vector_type(4)));

union U16 { half8 h; unsigned long long u[2]; };

// LDS layout (bytes)
#define XB_STR 136
#define B2_STR 136
#define YST_STR 72
#define Y2_STR 16
#define OFF_XB  0             // 2 x 64 x 136 halves = 34816
#define OFF_B2  34816         // 17408
#define OFF_YST 52224         // 9216
#define OFF_Y2  61440         // 2048 (aliased as HTX after mid-step sync)
#define OFF_FR  63488         // 448 floats
#define SMEM_BYTES 65280

#define SPIN_MAX (1 << 20)

#define A_LOAD(p)  __hip_atomic_load((p),  __ATOMIC_RELAXED, __HIP_MEMORY_SCOPE_AGENT)
#define A_STORE(p, v) __hip_atomic_store((p), (v), __ATOMIC_RELAXED, __HIP_MEMORY_SCOPE_AGENT)

// ws map: [0,4096) flags[8][32] spaced 4 dwords; [4096, +2x512KB) hbuf double
// buffer, slice-major: par*524288 + slice*16384 + row*32 (16 f16 cols/slice).

__device__ __forceinline__ float fast_sigmoid(float v) {
  v = fminf(fmaxf(v, -30.f), 30.f);
  return __builtin_amdgcn_rcpf(1.f + __expf(-v));
}
__device__ __forceinline__ float fast_tanh(float v) {
  v = fminf(fmaxf(v, -15.f), 15.f);
  float e = __expf(-2.f * v);
  return (1.f - e) * __builtin_amdgcn_rcpf(1.f + e);
}

__global__ void __launch_bounds__(256, 1)
lstm_persist(const float* __restrict__ x, const float* __restrict__ pos,
             const float* __restrict__ h0, const float* __restrict__ c0,
             const float* __restrict__ Wih, const float* __restrict__ Whh,
             const float* __restrict__ bih, const float* __restrict__ bhh,
             const float* __restrict__ W1, const float* __restrict__ b1,
             const float* __restrict__ W2, const float* __restrict__ b2,
             const float* __restrict__ W3, const float* __restrict__ b3,
             float* __restrict__ out, void* __restrict__ ws)
{
  extern __shared__ char smem[];
  _Float16* B2s = (_Float16*)(smem + OFF_B2);
  _Float16* YST = (_Float16*)(smem + OFF_YST);
  _Float16* Y2  = (_Float16*)(smem + OFF_Y2);
  _Float16* HTX = Y2;   // reuse: Y2 dead before HTX writes begin
  float* FR  = (float*)(smem + OFF_FR);
  float* b1s = FR;          // 64
  float* b2s = FR + 64;     // 16
  float* w3s = FR + 80;     // 32
  float* b3s = FR + 112;    // 2
  float* wy0 = FR + 114;    // 64
  float* wy1 = FR + 178;    // 64
  float* bgs = FR + 242;    // 64
  float* ypres = FR + 306;  // 128
  volatile int* abflag = (volatile int*)(FR + 440);

  const int tid = threadIdx.x;
  const int g  = blockIdx.x >> 5;   // batch group: rows 64g..64g+63
  const int cs = blockIdx.x & 31;   // h-column slice: 16cs..16cs+15
  const int w  = tid >> 6, l = tid & 63;
  const int c16 = l & 15, q = l >> 4;
  const int rh = w >> 1;            // row half (32 rows)
  const int ch = w & 1;             // 0 = gates, 1 = MLP(W1)

  unsigned* flags = (unsigned*)ws;
  char* hbase = (char*)ws + 4096;

  if (tid == 0) *abflag = 0;
  // ---- zero xbuf (incl. zero-pad cols 103..127) ----
  {
    unsigned* xz = (unsigned*)(smem + OFF_XB);
    for (int i = tid; i < 8704; i += 256) xz[i] = 0;
  }
  // ---- W_ih x-part -> LDS fp16 ----
  for (int idx = tid; idx < 64 * 128; idx += 256) {
    int cc = idx >> 7, k = idx & 127;
    int gr = (cc >> 4) * NH + cs * 16 + (cc & 15);
    float v = (k < NK) ? Wih[(size_t)gr * NI + k] : 0.f;
    B2s[cc * B2_STR + k] = (_Float16)v;
  }
  // ---- small fp32 tables ----
  if (tid < 64) {
    int gr = (tid >> 4) * NH + cs * 16 + (tid & 15);
    wy0[tid] = Wih[(size_t)gr * NI + 103];
    wy1[tid] = Wih[(size_t)gr * NI + 104];
    bgs[tid] = bih[gr] + bhh[gr];
    b1s[tid] = b1[tid];
  }
  if (tid < 16) b2s[tid] = b2[tid];
  if (tid < 32) w3s[tid] = W3[tid];
  if (tid < 2)  b3s[tid] = b3[tid];

  // ---- h0 -> hbuf[0] slice cs (agent stores -> MALL) ----
  {
    const int r = tid >> 2, hb = tid & 3;
    const float* src = h0 + (size_t)(64 * g + r) * NH + cs * 16 + hb * 4;
    union { unsigned long long u; half4 h; } cv;
    cv.h[0] = (_Float16)src[0]; cv.h[1] = (_Float16)src[1];
    cv.h[2] = (_Float16)src[2]; cv.h[3] = (_Float16)src[3];
    A_STORE((unsigned long long*)(hbase + (size_t)cs * 16384
                                  + (size_t)(64 * g + r) * 32 + hb * 8), cv.u);
  }

  // ---- B weight fragments -> registers (held all 512 steps) ----
  half8 bfr[4][16];
  #pragma unroll
  for (int ct = 0; ct < 4; ++ct) {
    const int rown = ch ? (ct * 16 + c16) : (ct * NH + cs * 16 + c16);
    const float* rp = (ch ? W1 : Whh) + (size_t)rown * NH;
    #pragma unroll
    for (int kk = 0; kk < 16; ++kk) {
      const float* p = rp + kk * 32 + q * 8;
      floatx4 f0 = *(const floatx4*)(p);
      floatx4 f1 = *(const floatx4*)(p + 4);
      half8 hv;
      hv[0]=(_Float16)f0[0]; hv[1]=(_Float16)f0[1]; hv[2]=(_Float16)f0[2]; hv[3]=(_Float16)f0[3];
      hv[4]=(_Float16)f1[0]; hv[5]=(_Float16)f1[1]; hv[6]=(_Float16)f1[2]; hv[7]=(_Float16)f1[3];
      bfr[ct][kk] = hv;
    }
  }
  half8 w2f[2];
  if (ch) {
    #pragma unroll
    for (int kk = 0; kk < 2; ++kk) {
      const float* p = W2 + c16 * 64 + kk * 32 + q * 8;
      floatx4 f0 = *(const floatx4*)(p);
      floatx4 f1 = *(const floatx4*)(p + 4);
      half8 hv;
      hv[0]=(_Float16)f0[0]; hv[1]=(_Float16)f0[1]; hv[2]=(_Float16)f0[2]; hv[3]=(_Float16)f0[3];
      hv[4]=(_Float16)f1[0]; hv[5]=(_Float16)f1[1]; hv[6]=(_Float16)f1[2]; hv[7]=(_Float16)f1[3];
      w2f[kk] = hv;
    }
  }
  float cacc[2][4];
  if (!ch) {
    #pragma unroll
    for (int rt = 0; rt < 2; ++rt)
      #pragma unroll
      for (int reg = 0; reg < 4; ++reg)
        cacc[rt][reg] = c0[(size_t)(64 * g + 32 * rh + 16 * rt + q * 4 + reg) * NH + cs * 16 + c16];
  }

  // coalesced x_t -> LDS f16 stager (gate waves; 2 lanes per row)
  auto xstage = [&](int t1) {
    _Float16* xb = (_Float16*)(smem + OFF_XB) + (size_t)(t1 & 1) * 64 * XB_STR;
    const int row = 32 * rh + (l >> 1);
    const int p = l & 1;
    const float* src = x + (size_t)(64 * g + row) * XROW + (size_t)t1 * NK + p * 52;
    _Float16* dst = xb + row * XB_STR + p * 52;
    const int nfull = p ? 12 : 13;
    for (int cnk = 0; cnk < nfull; ++cnk) {
      float f0 = src[cnk * 4 + 0], f1 = src[cnk * 4 + 1];
      float f2 = src[cnk * 4 + 2], f3 = src[cnk * 4 + 3];
      half4 hv; hv[0]=(_Float16)f0; hv[1]=(_Float16)f1; hv[2]=(_Float16)f2; hv[3]=(_Float16)f3;
      *(half4*)(dst + cnk * 4) = hv;
    }
    if (p) {
      dst[48] = (_Float16)src[48];
      dst[49] = (_Float16)src[49];
      dst[50] = (_Float16)src[50];
    }
  };

  // flag publish: caller guarantees a prior __syncthreads drained publishes
  auto fpub = [&](unsigned val) {
    if (tid == 0) A_STORE(flags + ((g << 5) + cs) * 4, val);
  };

  __syncthreads();          // init LDS + h0 stores drained (barrier waits vmcnt)
  if (!ch) xstage(0);       // x_0 -> xbuf[0]
  __syncthreads();
  fpub(1);                  // h0 slice published

  // iter t: per-wave dataflow poll; batched A-loads; phase2 overlaps in-flight
  // loads; MLP waves finish y_{t-1}; gate waves update c -> h_t; publish.
  for (int t = 0; t <= NL; ++t) {
    // ---- per-wave poll: wait for all 32 producers of h_{t-1} (flag >= t+1) ----
    if (l < 32) {
      unsigned* f = flags + ((g << 5) + l) * 4;
      int spins = 0;
      while (A_LOAD(f) < (unsigned)(t + 1)) {
        if (++spins > SPIN_MAX) { *abflag = 1; break; }  // checked at uniform point below
      }
    }

    // ---- issue all A-loads (slice-major, lane-contiguous, 64 x 8B) ----
    U16 ar[2][16];
    {
      const char* lb = hbase + (size_t)(t & 1) * 524288
                     + (size_t)(q >> 1) * 16384
                     + (size_t)(64 * g + 32 * rh + c16) * 32 + (q & 1) * 16;
      #pragma unroll
      for (int kk = 0; kk < 16; ++kk) {
        #pragma unroll
        for (int rt = 0; rt < 2; ++rt) {
          const unsigned long long* up =
              (const unsigned long long*)(lb + (size_t)kk * 32768 + rt * 512);
          ar[rt][kk].u[0] = A_LOAD(up);
          ar[rt][kk].u[1] = A_LOAD(up + 1);
        }
      }
    }

    floatx4 acc[4][2] = {};

    // ---- phase 2 (gate waves): x_t from LDS — overlaps in-flight A-loads ----
    if (!ch && t < NL) {
      const _Float16* xb = (const _Float16*)(smem + OFF_XB) + (size_t)(t & 1) * 64 * XB_STR;
      #pragma unroll
      for (int kb = 0; kb < 4; ++kb) {
        half8 ax[2];
        #pragma unroll
        for (int rt = 0; rt < 2; ++rt)
          ax[rt] = *(const half8*)(xb + (32 * rh + 16 * rt + c16) * XB_STR + kb * 32 + q * 8);
        #pragma unroll
        for (int ct = 0; ct < 4; ++ct) {
          half8 bf = *(const half8*)(B2s + (ct * 16 + c16) * B2_STR + kb * 32 + q * 8);
          #pragma unroll
          for (int rt = 0; rt < 2; ++rt)
            acc[ct][rt] = __builtin_amdgcn_mfma_f32_16x16x32_f16(ax[rt], bf, acc[ct][rt], 0, 0, 0);
        }
      }
      if (t + 1 < NL) xstage(t + 1);
    }

    // ---- phase 1: K=512 over h_{t-1}; A from regs, B from regs ----
    #pragma unroll
    for (int kk = 0; kk < 16; ++kk)
      #pragma unroll
      for (int ct = 0; ct < 4; ++ct) {
        acc[ct][0] = __builtin_amdgcn_mfma_f32_16x16x32_f16(ar[0][kk].h, bfr[ct][kk], acc[ct][0], 0, 0, 0);
        acc[ct][1] = __builtin_amdgcn_mfma_f32_16x16x32_f16(ar[1][kk].h, bfr[ct][kk], acc[ct][1], 0, 0, 0);
      }

    // ---- MLP waves: y_{t-1} (or pos init at t==0) ----
    if (ch) {
      if (t == 0) {
        if (l < 32) {
          int row = 32 * rh + l;
          const float* pp = pos + (size_t)(64 * g + row) * (NL * 2);
          ypres[row * 2 + 0] = pp[0];
          ypres[row * 2 + 1] = pp[1];
        }
      } else {
        #pragma unroll
        for (int ct = 0; ct < 4; ++ct)
          #pragma unroll
          for (int rt = 0; rt < 2; ++rt)
            #pragma unroll
            for (int reg = 0; reg < 4; ++reg) {
              int row = 32 * rh + 16 * rt + q * 4 + reg;
              float v = acc[ct][rt][reg] + b1s[ct * 16 + c16];
              YST[row * YST_STR + ct * 16 + c16] = (_Float16)fmaxf(v, 0.f);
            }
        floatx4 a2c[2] = {};
        #pragma unroll
        for (int kk2 = 0; kk2 < 2; ++kk2)
          #pragma unroll
          for (int rt = 0; rt < 2; ++rt) {
            half8 af = *(const half8*)(YST + (32 * rh + 16 * rt + c16) * YST_STR + kk2 * 32 + q * 8);
            a2c[rt] = __builtin_amdgcn_mfma_f32_16x16x32_f16(af, w2f[kk2], a2c[rt], 0, 0, 0);
          }
        #pragma unroll
        for (int rt = 0; rt < 2; ++rt)
          #pragma unroll
          for (int reg = 0; reg < 4; ++reg) {
            int row = 32 * rh + 16 * rt + q * 4 + reg;
            float v = a2c[rt][reg] + b2s[c16];
            Y2[row * Y2_STR + c16] = (_Float16)fmaxf(v, 0.f);
          }
        if (l < 32) {
          int row = 32 * rh + l;
          float y0 = b3s[0], y1 = b3s[1];
          #pragma unroll
          for (int k = 0; k < 16; ++k) {
            float vv = (float)Y2[row * Y2_STR + k];
            y0 += vv * w3s[k];
            y1 += vv * w3s[16 + k];
          }
          y0 = fmaxf(y0, 0.f); y1 = fmaxf(y1, 0.f);
          ypres[row * 2 + 0] = y0;
          ypres[row * 2 + 1] = y1;
          if (cs == 0) {
            float2* op = (float2*)(out + (size_t)(64 * g + row) * (NL * 2) + (size_t)(t - 1) * 2);
            *op = make_float2(y0, y1);
          }
        }
      }
    }
    __syncthreads();        // ypres ready; Y2 reads done (HTX may overwrite)
    if (*abflag) return;    // uniform abort point (poll timeout anywhere)

    // ---- gate epilogue: feedback + bias + LSTM cell; h_t -> LDS tile ----
    if (!ch && t < NL) {
      #pragma unroll
      for (int rt = 0; rt < 2; ++rt)
        #pragma unroll
        for (int reg = 0; reg < 4; ++reg) {
          int rl = 32 * rh + 16 * rt + q * 4 + reg;
          float yp0 = ypres[rl * 2], yp1 = ypres[rl * 2 + 1];
          float gi = acc[0][rt][reg] + bgs[c16]      + yp0 * wy0[c16]      + yp1 * wy1[c16];
          float gf = acc[1][rt][reg] + bgs[16 + c16] + yp0 * wy0[16 + c16] + yp1 * wy1[16 + c16];
          float gg = acc[2][rt][reg] + bgs[32 + c16] + yp0 * wy0[32 + c16] + yp1 * wy1[32 + c16];
          float go = acc[3][rt][reg] + bgs[48 + c16] + yp0 * wy0[48 + c16] + yp1 * wy1[48 + c16];
          float iv = fast_sigmoid(gi);
          float fv = fast_sigmoid(gf);
          float gv = fast_tanh(gg);
          float ov = fast_sigmoid(go);
          float cn = fv * cacc[rt][reg] + iv * gv;
          cacc[rt][reg] = cn;
          float hn = ov * fast_tanh(cn);
          HTX[rl * 16 + c16] = (_Float16)hn;
          if (t == NL - 1) {
            out[(size_t)(NB * NL * 2) + (size_t)(64 * g + rl) * NH + cs * 16 + c16] = hn;
            out[(size_t)(NB * NL * 2) + (size_t)(NB * NH) + (size_t)(64 * g + rl) * NH + cs * 16 + c16] = cn;
          }
        }
    }

    if (t < NL) {
      __syncthreads();  // HTX complete (and all reads of this iter's tile done)
      // publish h_t slice: 256 threads x 8B agent stores, slice-major
      {
        const int r = tid >> 2, hb = tid & 3;
        char* dst = hbase + (size_t)((t + 1) & 1) * 524288
                  + (size_t)cs * 16384 + (size_t)(64 * g + r) * 32 + hb * 8;
        unsigned long long v = *(const unsigned long long*)(HTX + r * 16 + hb * 4);
        A_STORE((unsigned long long*)dst, v);
      }
      __syncthreads();          // drain publishes (vmcnt 0 in every wave)
      fpub((unsigned)(t + 2));  // raise our flag for step t+1 consumers
    }
  }
}

extern "C" void kernel_launch(void* const* d_in, const int* in_sizes, int n_in,
                              void* d_out, int out_size, void* d_ws, size_t ws_size,
                              hipStream_t stream) {
  (void)in_sizes; (void)n_in; (void)out_size; (void)ws_size;
  const float* x   = (const float*)d_in[0];
  const float* pos = (const float*)d_in[1];
  const float* h0  = (const float*)d_in[2];
  const float* c0  = (const float*)d_in[3];
  const float* Wih = (const float*)d_in[4];
  const float* Whh = (const float*)d_in[5];
  const float* bih = (const float*)d_in[6];
  const float* bhh = (const float*)d_in[7];
  const float* W1  = (const float*)d_in[8];
  const float* b1  = (const float*)d_in[9];
  const float* W2  = (const float*)d_in[10];
  const float* b2  = (const float*)d_in[11];
  const float* W3  = (const float*)d_in[12];
  const float* b3  = (const float*)d_in[13];
  float* out = (float*)d_out;

  hipMemsetAsync(d_ws, 0, 4096, stream);  // flags

  void* args[] = { (void*)&x, (void*)&pos, (void*)&h0, (void*)&c0,
                   (void*)&Wih, (void*)&Whh, (void*)&bih, (void*)&bhh,
                   (void*)&W1, (void*)&b1, (void*)&W2, (void*)&b2,
                   (void*)&W3, (void*)&b3, (void*)&out, (void*)&d_ws };

  hipError_t err = hipLaunchCooperativeKernel(
      reinterpret_cast<void*>(lstm_persist),
      dim3(256, 1, 1), dim3(256, 1, 1), args, (unsigned)SMEM_BYTES, stream);
  if (err != hipSuccess) {
    (void)hipGetLastError();
    lstm_persist<<<dim3(256, 1, 1), dim3(256, 1, 1), SMEM_BYTES, stream>>>(
        x, pos, h0, c0, Wih, Whh, bih, bhh, W1, b1, W2, b2, W3, b3, out, d_ws);
  }
}